// Round 4
// baseline (570.723 us; speedup 1.0000x reference)
//
#include <hip/hip_runtime.h>
#include <hip/hip_bf16.h>
#include <stdint.h>

// B=32, S=2048, DK=DV=64, fp32 in/out. out = [output (B,S,64) | attn (B,S,S)].
// Two-pass swapped-operand MFMA attention, zero LDS, zero barriers:
//   prepass: detect mask dtype; pack mask 1 bit/elem; K->bf16; V->Vt bf16.
//   main: QK^T as mfma(K,Q) -> D col=query,row=key. Lane owns 8 consecutive
//   keys of one query row -> register-direct f32x4 attn stores, scalar row
//   sum (2 shuffles), PV A-frag via 8 ds_bpermute. K/Vt read straight from
//   L2 (fully resident), double-buffered in registers.

#define B_ 32
#define S_ 2048
#define D_ 64

typedef float   f32x4  __attribute__((ext_vector_type(4)));
typedef __bf16  bf16x8 __attribute__((ext_vector_type(8)));
typedef unsigned short u16x4 __attribute__((ext_vector_type(4)));

__device__ __forceinline__ unsigned short f2bf(float f) {
  unsigned u = __float_as_uint(f);
  u = (u + 0x7FFFu + ((u >> 16) & 1u)) >> 16;   // RNE
  return (unsigned short)u;
}

__device__ __forceinline__ unsigned pack2bf(float a, float b) {
  union { __bf16 h[2]; unsigned u; } r;
  r.h[0] = (__bf16)a; r.h[1] = (__bf16)b;
  return r.u;
}

// ---------------- mask dtype detection ----------------
__global__ void detect_mask(const unsigned* __restrict__ m, int* __restrict__ flag) {
  if (threadIdx.x == 0 && blockIdx.x == 0) {
    int wide = 1;
    for (int i = 0; i < 64; ++i) {
      unsigned w = m[i];
      wide &= (w <= 1u || w == 0x3F800000u);
    }
    *flag = wide ? 1 : 0;
  }
}

// ---------------- mask bit-pack: 32 elems -> 1 uint ----------------
__global__ void pack_mask(const void* __restrict__ M, const int* __restrict__ flag,
                          unsigned* __restrict__ Mp) {
  size_t t = (size_t)blockIdx.x * 256 + threadIdx.x;
  unsigned bits = 0;
  if (*flag == 0) {
    const uint4* p = (const uint4*)((const uint8_t*)M + t * 32);
    uint4 a = p[0], b = p[1];
    unsigned w[8] = {a.x, a.y, a.z, a.w, b.x, b.y, b.z, b.w};
#pragma unroll
    for (int i = 0; i < 8; ++i)
#pragma unroll
      for (int j = 0; j < 4; ++j)
        bits |= (unsigned)(((w[i] >> (8 * j)) & 0xFFu) != 0u) << (i * 4 + j);
  } else {
    const uint4* p = (const uint4*)((const unsigned*)M + t * 32);
#pragma unroll
    for (int i = 0; i < 8; ++i) {
      uint4 a = p[i];
      bits |= (unsigned)(a.x != 0u) << (i * 4 + 0);
      bits |= (unsigned)(a.y != 0u) << (i * 4 + 1);
      bits |= (unsigned)(a.z != 0u) << (i * 4 + 2);
      bits |= (unsigned)(a.w != 0u) << (i * 4 + 3);
    }
  }
  Mp[t] = bits;
}

// ---------------- K fp32 -> bf16 cast ----------------
__global__ void cast_k(const float* __restrict__ K, unsigned short* __restrict__ Kbf) {
  size_t i = ((size_t)blockIdx.x * 256 + threadIdx.x) * 4;
  f32x4 v = *reinterpret_cast<const f32x4*>(K + i);
  u16x4 o;
  o[0] = f2bf(v[0]); o[1] = f2bf(v[1]); o[2] = f2bf(v[2]); o[3] = f2bf(v[3]);
  *reinterpret_cast<u16x4*>(Kbf + i) = o;
}

// ---------------- V -> Vt (d-major) bf16 transpose ----------------
__global__ void transpose_v(const float* __restrict__ V, unsigned short* __restrict__ Vt) {
  __shared__ float tile[32][33];
  int b = blockIdx.z, k0 = blockIdx.x * 32, d0 = blockIdx.y * 32;
  int tx = threadIdx.x, ty = threadIdx.y;
  const float* src = V + ((size_t)b * S_ + k0) * D_ + d0;
  for (int r = 0; r < 4; ++r) {
    int yy = ty + r * 8;
    tile[yy][tx] = src[(size_t)yy * D_ + tx];
  }
  __syncthreads();
  unsigned short* dst = Vt + ((size_t)b * D_ + d0) * S_ + k0;
  for (int r = 0; r < 4; ++r) {
    int yy = ty + r * 8;
    dst[(size_t)yy * S_ + tx] = f2bf(tile[tx][yy]);
  }
}

// ---------------- main attention ----------------
#define MFMA16(A, B, C) __builtin_amdgcn_mfma_f32_16x16x32_bf16(A, B, C, 0, 0, 0)

// load the 4 K-fragments of 32-key tile kc_ (A-operand: row=key=lo, k=d)
#define KLOAD(kc_, r0, r1, r2, r3)                                       \
  {                                                                      \
    const unsigned short* _p = kp + (size_t)(kc_) * (32 * D_);           \
    r0 = *reinterpret_cast<const bf16x8*>(_p);                           \
    r1 = *reinterpret_cast<const bf16x8*>(_p + 32);                      \
    r2 = *reinterpret_cast<const bf16x8*>(_p + 16 * D_);                 \
    r3 = *reinterpret_cast<const bf16x8*>(_p + 16 * D_ + 32);            \
  }

#define P1STEP(mw_, r0, r1, r2, r3)                                      \
  {                                                                      \
    f32x4 a0 = {0.f,0.f,0.f,0.f}, a1 = {0.f,0.f,0.f,0.f};                \
    a0 = MFMA16(r0, bq0, a0); a0 = MFMA16(r1, bq1, a0);                  \
    a1 = MFMA16(r2, bq0, a1); a1 = MFMA16(r3, bq1, a1);                  \
    _Pragma("unroll")                                                    \
    for (int i = 0; i < 4; ++i) {                                        \
      float e0 = ((mw_ >> (4 * hi + i)) & 1u) ? 0.f : __expf(a0[i]);     \
      float e1 = ((mw_ >> (16 + 4 * hi + i)) & 1u) ? 0.f : __expf(a1[i]);\
      lsum += e0 + e1;                                                   \
    }                                                                    \
  }

#define P2STEP(kc_, mw_, r0, r1, r2, r3)                                 \
  {                                                                      \
    f32x4 a0 = {0.f,0.f,0.f,0.f}, a1 = {0.f,0.f,0.f,0.f};                \
    a0 = MFMA16(r0, bq0, a0); a0 = MFMA16(r1, bq1, a0);                  \
    a1 = MFMA16(r2, bq0, a1); a1 = MFMA16(r3, bq1, a1);                  \
    bf16x8 v0 = *reinterpret_cast<const bf16x8*>(vp0 + (kc_) * 32);      \
    bf16x8 v1 = *reinterpret_cast<const bf16x8*>(vp1 + (kc_) * 32);      \
    bf16x8 v2 = *reinterpret_cast<const bf16x8*>(vp2 + (kc_) * 32);      \
    bf16x8 v3 = *reinterpret_cast<const bf16x8*>(vp3 + (kc_) * 32);      \
    f32x4 p0, p1;                                                        \
    _Pragma("unroll")                                                    \
    for (int i = 0; i < 4; ++i) {                                        \
      p0[i] = ((mw_ >> (4 * hi + i)) & 1u) ? 0.f : __expf(a0[i]) * rinv; \
      p1[i] = ((mw_ >> (16 + 4 * hi + i)) & 1u) ? 0.f : __expf(a1[i]) * rinv;\
    }                                                                    \
    __builtin_nontemporal_store(p0,                                      \
        reinterpret_cast<f32x4*>(sp + (kc_) * 32 + 4 * hi));             \
    __builtin_nontemporal_store(p1,                                      \
        reinterpret_cast<f32x4*>(sp + (kc_) * 32 + 16 + 4 * hi));        \
    unsigned pk0 = pack2bf(p0[0], p0[1]), pk1 = pack2bf(p0[2], p0[3]);   \
    unsigned pk2 = pack2bf(p1[0], p1[1]), pk3 = pack2bf(p1[2], p1[3]);   \
    unsigned t00 = (unsigned)__shfl((int)pk0, s0, 64);                   \
    unsigned t20 = (unsigned)__shfl((int)pk2, s0, 64);                   \
    unsigned t10 = (unsigned)__shfl((int)pk1, s0, 64);                   \
    unsigned t30 = (unsigned)__shfl((int)pk3, s0, 64);                   \
    unsigned t01 = (unsigned)__shfl((int)pk0, s1, 64);                   \
    unsigned t21 = (unsigned)__shfl((int)pk2, s1, 64);                   \
    unsigned t11 = (unsigned)__shfl((int)pk1, s1, 64);                   \
    unsigned t31 = (unsigned)__shfl((int)pk3, s1, 64);                   \
    uint4 dw;                                                            \
    dw.x = hl ? t00 : t20; dw.y = hl ? t10 : t30;                        \
    dw.z = hl ? t01 : t21; dw.w = hl ? t11 : t31;                        \
    bf16x8 pa = __builtin_bit_cast(bf16x8, dw);                          \
    oacc[0] = MFMA16(pa, v0, oacc[0]);                                   \
    oacc[1] = MFMA16(pa, v1, oacc[1]);                                   \
    oacc[2] = MFMA16(pa, v2, oacc[2]);                                   \
    oacc[3] = MFMA16(pa, v3, oacc[3]);                                   \
  }

__global__ __launch_bounds__(256, 4) void attn_main4(
    const float* __restrict__ Q, const unsigned short* __restrict__ Kbf,
    const unsigned* __restrict__ Mp, const unsigned short* __restrict__ Vt,
    float* __restrict__ Out) {
  int wg = blockIdx.x;                       // 1024 wgs
  int vdx = (wg & 7) * 128 + (wg >> 3);      // XCD-contiguous remap (bijective)
  int b = vdx >> 5, qt = vdx & 31;
  int wave = threadIdx.x >> 6, lane = threadIdx.x & 63;
  int q0 = qt * 64 + wave * 16;
  const int lo = lane & 15, hi = lane >> 4;
  const int s0 = lo + (((2 * hi) & 3) << 4);
  const int s1 = lo + (((2 * hi + 1) & 3) << 4);
  const bool hl = hi < 2;

  const float* Qb = Q + (size_t)b * S_ * D_;
  const unsigned short* Kb = Kbf + (size_t)b * S_ * D_;
  const unsigned short* Vtb = Vt + (size_t)b * D_ * S_;
  const unsigned* mptr = Mp + ((size_t)b * S_ + q0 + lo) * (S_ / 32);
  float* outO = Out + (size_t)b * S_ * D_;
  float* sp = Out + (size_t)B_ * S_ * D_ + ((size_t)b * S_ + q0 + lo) * S_;

  // Q B-fragments (temperature folded: /8 is exact in fp): col=query=lo,
  // k-element j of frag kb = d = kb*32 + hi*8 + j
  bf16x8 bq0, bq1;
  {
    const float* qr = Qb + (size_t)(q0 + lo) * D_ + hi * 8;
    f32x4 x0 = *reinterpret_cast<const f32x4*>(qr);
    f32x4 y0 = *reinterpret_cast<const f32x4*>(qr + 4);
    f32x4 x1 = *reinterpret_cast<const f32x4*>(qr + 32);
    f32x4 y1 = *reinterpret_cast<const f32x4*>(qr + 36);
#pragma unroll
    for (int j = 0; j < 4; ++j) {
      bq0[j] = (__bf16)(x0[j] * 0.125f); bq0[j + 4] = (__bf16)(y0[j] * 0.125f);
      bq1[j] = (__bf16)(x1[j] * 0.125f); bq1[j + 4] = (__bf16)(y1[j] * 0.125f);
    }
  }

  const unsigned short* kp = Kb + (size_t)lo * D_ + hi * 8;  // key row = lo

  // ================= pass 1: denominators =================
  float lsum = 0.f;
  {
    bf16x8 ka0, ka1, ka2, ka3, kb0, kb1, kb2, kb3;
    unsigned mwA = mptr[0], mwB;
    KLOAD(0, ka0, ka1, ka2, ka3);
    for (int kc = 0; kc < 62; kc += 2) {
      KLOAD(kc + 1, kb0, kb1, kb2, kb3); mwB = mptr[kc + 1];
      P1STEP(mwA, ka0, ka1, ka2, ka3);
      KLOAD(kc + 2, ka0, ka1, ka2, ka3); mwA = mptr[kc + 2];
      P1STEP(mwB, kb0, kb1, kb2, kb3);
    }
    KLOAD(63, kb0, kb1, kb2, kb3); mwB = mptr[63];
    P1STEP(mwA, ka0, ka1, ka2, ka3);
    P1STEP(mwB, kb0, kb1, kb2, kb3);
  }
  lsum += __shfl_xor(lsum, 16, 64);
  lsum += __shfl_xor(lsum, 32, 64);
  const float rinv = 1.0f / lsum;

  // ================= pass 2: attn write + PV =================
  f32x4 oacc[4];
#pragma unroll
  for (int db = 0; db < 4; ++db) {
    oacc[db][0] = 0.f; oacc[db][1] = 0.f; oacc[db][2] = 0.f; oacc[db][3] = 0.f;
  }
  const unsigned short* vp0 = Vtb + (size_t)(lo) * S_ + hi * 8;
  const unsigned short* vp1 = vp0 + (size_t)16 * S_;
  const unsigned short* vp2 = vp0 + (size_t)32 * S_;
  const unsigned short* vp3 = vp0 + (size_t)48 * S_;

  {
    bf16x8 ka0, ka1, ka2, ka3, kb0, kb1, kb2, kb3;
    unsigned mwA = mptr[0], mwB;
    KLOAD(0, ka0, ka1, ka2, ka3);
    for (int kc = 0; kc < 62; kc += 2) {
      KLOAD(kc + 1, kb0, kb1, kb2, kb3); mwB = mptr[kc + 1];
      P2STEP(kc, mwA, ka0, ka1, ka2, ka3);
      KLOAD(kc + 2, ka0, ka1, ka2, ka3); mwA = mptr[kc + 2];
      P2STEP(kc + 1, mwB, kb0, kb1, kb2, kb3);
    }
    KLOAD(63, kb0, kb1, kb2, kb3); mwB = mptr[63];
    P2STEP(62, mwA, ka0, ka1, ka2, ka3);
    P2STEP(63, mwB, kb0, kb1, kb2, kb3);
  }

  // epilogue: O store. D col=d16=lo, row=query=hi*4+i
#pragma unroll
  for (int db = 0; db < 4; ++db)
#pragma unroll
    for (int i = 0; i < 4; ++i)
      __builtin_nontemporal_store(oacc[db][i],
          outO + (size_t)(q0 + hi * 4 + i) * D_ + db * 16 + lo);
}

extern "C" void kernel_launch(void* const* d_in, const int* in_sizes, int n_in,
                              void* d_out, int out_size, void* d_ws, size_t ws_size,
                              hipStream_t stream) {
  const float* q = (const float*)d_in[0];
  const float* k = (const float*)d_in[1];
  const float* v = (const float*)d_in[2];
  const void*  m = d_in[3];
  float* out = (float*)d_out;

  // ws: [0] flag; [256] Vt bf16 (8MB); [+8MB] Kbf bf16 (8MB); [+8MB] Mp (16MB)
  int* flag = (int*)d_ws;
  unsigned short* Vt  = (unsigned short*)((char*)d_ws + 256);
  unsigned short* Kbf = (unsigned short*)((char*)d_ws + 256 + (size_t)B_ * D_ * S_ * 2);
  unsigned*       Mp  = (unsigned*)((char*)d_ws + 256 + (size_t)B_ * D_ * S_ * 4);

  detect_mask<<<1, 64, 0, stream>>>((const unsigned*)m, flag);
  cast_k<<<(B_ * S_ * D_) / (256 * 4), 256, 0, stream>>>(k, Kbf);
  transpose_v<<<dim3(S_ / 32, D_ / 32, B_), dim3(32, 8), 0, stream>>>(v, Vt);
  pack_mask<<<(B_ * S_ * (S_ / 32)) / 256, 256, 0, stream>>>(m, flag, Mp);
  attn_main4<<<B_ * (S_ / 64), 256, 0, stream>>>(q, Kbf, Mp, Vt, out);
}

// Round 5
// 376.335 us; speedup vs baseline: 1.5165x; 1.5165x over previous
//
#include <hip/hip_runtime.h>
#include <hip/hip_bf16.h>
#include <stdint.h>

// B=32, S=2048, DK=DV=64, fp32 in/out. out = [output (B,S,64) | attn (B,S,S)].
// Fused two-phase swapped-operand MFMA attention:
//   prepass: detect mask dtype; pack mask 1 bit/elem; K->bf16; V->Vt bf16.
//   phase 1: 16 x 128-key tiles, WG-staged K (global_load_lds, dbuf, swizzled)
//            QK^T = mfma(K,Q) -> lane owns keys of ONE query row; masked exp
//            -> row sum -> scalar rinv (2 shuffles).
//   phase 2: 32 x 64-key tiles, WG-staged K+Vt; recompute scores, register-
//            direct f32x4 attn stores, P regroup via 8 shuffles, PV MFMA.

#define B_ 32
#define S_ 2048
#define D_ 64

typedef float   f32x4  __attribute__((ext_vector_type(4)));
typedef __bf16  bf16x8 __attribute__((ext_vector_type(8)));
typedef unsigned short u16x4 __attribute__((ext_vector_type(4)));

__device__ __forceinline__ unsigned short f2bf(float f) {
  unsigned u = __float_as_uint(f);
  u = (u + 0x7FFFu + ((u >> 16) & 1u)) >> 16;   // RNE
  return (unsigned short)u;
}

__device__ __forceinline__ unsigned pack2bf(float a, float b) {
  union { __bf16 h[2]; unsigned u; } r;
  r.h[0] = (__bf16)a; r.h[1] = (__bf16)b;
  return r.u;
}

__device__ __forceinline__ void load_lds16(const void* g, void* l) {
  __builtin_amdgcn_global_load_lds(
      (const __attribute__((address_space(1))) unsigned*)g,
      (__attribute__((address_space(3))) unsigned*)l, 16, 0, 0);
}

// ---------------- mask dtype detection ----------------
__global__ void detect_mask(const unsigned* __restrict__ m, int* __restrict__ flag) {
  if (threadIdx.x == 0 && blockIdx.x == 0) {
    int wide = 1;
    for (int i = 0; i < 64; ++i) {
      unsigned w = m[i];
      wide &= (w <= 1u || w == 0x3F800000u);
    }
    *flag = wide ? 1 : 0;
  }
}

// ---------------- mask bit-pack: 32 elems -> 1 uint ----------------
__global__ void pack_mask(const void* __restrict__ M, const int* __restrict__ flag,
                          unsigned* __restrict__ Mp) {
  size_t t = (size_t)blockIdx.x * 256 + threadIdx.x;
  unsigned bits = 0;
  if (*flag == 0) {
    const uint4* p = (const uint4*)((const uint8_t*)M + t * 32);
    uint4 a = p[0], b = p[1];
    unsigned w[8] = {a.x, a.y, a.z, a.w, b.x, b.y, b.z, b.w};
#pragma unroll
    for (int i = 0; i < 8; ++i)
#pragma unroll
      for (int j = 0; j < 4; ++j)
        bits |= (unsigned)(((w[i] >> (8 * j)) & 0xFFu) != 0u) << (i * 4 + j);
  } else {
    const uint4* p = (const uint4*)((const unsigned*)M + t * 32);
#pragma unroll
    for (int i = 0; i < 8; ++i) {
      uint4 a = p[i];
      bits |= (unsigned)(a.x != 0u) << (i * 4 + 0);
      bits |= (unsigned)(a.y != 0u) << (i * 4 + 1);
      bits |= (unsigned)(a.z != 0u) << (i * 4 + 2);
      bits |= (unsigned)(a.w != 0u) << (i * 4 + 3);
    }
  }
  Mp[t] = bits;
}

// ---------------- K fp32 -> bf16 cast ----------------
__global__ void cast_k(const float* __restrict__ K, unsigned short* __restrict__ Kbf) {
  size_t i = ((size_t)blockIdx.x * 256 + threadIdx.x) * 4;
  f32x4 v = *reinterpret_cast<const f32x4*>(K + i);
  u16x4 o;
  o[0] = f2bf(v[0]); o[1] = f2bf(v[1]); o[2] = f2bf(v[2]); o[3] = f2bf(v[3]);
  *reinterpret_cast<u16x4*>(Kbf + i) = o;
}

// ---------------- V -> Vt (d-major) bf16 transpose ----------------
__global__ void transpose_v(const float* __restrict__ V, unsigned short* __restrict__ Vt) {
  __shared__ float tile[32][33];
  int b = blockIdx.z, k0 = blockIdx.x * 32, d0 = blockIdx.y * 32;
  int tx = threadIdx.x, ty = threadIdx.y;
  const float* src = V + ((size_t)b * S_ + k0) * D_ + d0;
  for (int r = 0; r < 4; ++r) {
    int yy = ty + r * 8;
    tile[yy][tx] = src[(size_t)yy * D_ + tx];
  }
  __syncthreads();
  unsigned short* dst = Vt + ((size_t)b * D_ + d0) * S_ + k0;
  for (int r = 0; r < 4; ++r) {
    int yy = ty + r * 8;
    dst[(size_t)yy * S_ + tx] = f2bf(tile[tx][yy]);
  }
}

// ---------------- main attention ----------------
#define MFMA16(A, B, C) __builtin_amdgcn_mfma_f32_16x16x32_bf16(A, B, C, 0, 0, 0)

__global__ __launch_bounds__(256, 4) void attn_main5(
    const float* __restrict__ Q, const unsigned short* __restrict__ Kbf,
    const unsigned* __restrict__ Mp, const unsigned short* __restrict__ Vt,
    float* __restrict__ Out) {
  // 32 KB LDS, phase-dependent layout (all 16B-slot XOR-swizzled, slot^=row&7):
  //   phase 1: K[2][128*64] bf16 (2 x 16 KB)
  //   phase 2: K[2][64*64] (2 x 8 KB) | Vt[2][64*64] (2 x 8 KB) at +8192
  __shared__ __align__(16) unsigned short smem[16384];

  const int t = threadIdx.x;
  int wg = blockIdx.x;                       // 1024 wgs
  int vdx = (wg & 7) * 128 + (wg >> 3);      // XCD-contiguous remap (bijective)
  int b = vdx >> 5, qt = vdx & 31;
  int wave = t >> 6, lane = t & 63;
  int q0 = qt * 64 + wave * 16;
  const int lo = lane & 15, hi = lane >> 4;
  const int s0 = lo + (((2 * hi) & 3) << 4);
  const int s1 = lo + (((2 * hi + 1) & 3) << 4);
  const bool hl = hi < 2;

  const unsigned short* Kb  = Kbf + (size_t)b * S_ * D_;
  const unsigned short* Vtb = Vt  + (size_t)b * D_ * S_;
  const unsigned* mptr = Mp + ((size_t)b * S_ + q0 + lo) * (S_ / 32);
  float* outO = Out + (size_t)b * S_ * D_;
  float* sp   = Out + (size_t)B_ * S_ * D_ + ((size_t)b * S_ + q0 + lo) * S_;

  // Q B-fragments (temperature folded): col=query=lo, k-elem j of half kb
  // = d = kb*32 + hi*8 + j
  bf16x8 bq0, bq1;
  {
    const float* qr = Q + ((size_t)b * S_ + q0 + lo) * D_ + hi * 8;
    f32x4 x0 = *reinterpret_cast<const f32x4*>(qr);
    f32x4 y0 = *reinterpret_cast<const f32x4*>(qr + 4);
    f32x4 x1 = *reinterpret_cast<const f32x4*>(qr + 32);
    f32x4 y1 = *reinterpret_cast<const f32x4*>(qr + 36);
#pragma unroll
    for (int j = 0; j < 4; ++j) {
      bq0[j] = (__bf16)(x0[j] * 0.125f); bq0[j + 4] = (__bf16)(y0[j] * 0.125f);
      bq1[j] = (__bf16)(x1[j] * 0.125f); bq1[j + 4] = (__bf16)(y1[j] * 0.125f);
    }
  }

  // staging sources (inverse-swizzled): thread t fills LDS slot t (linear)
  const int sr = t >> 3, sj = t & 7;
  const unsigned short* kg = Kb  + (size_t)sr * D_ + ((sj ^ (sr & 7)) << 3);
  const unsigned short* vg = Vtb + (size_t)sr * S_ + ((sj ^ (sr & 7)) << 3);

  // swizzled fragment read offsets (row stride 64 elems, slot = 8 elems)
  const int sw = lo & 7;
  const int offA0 = lo * 64 + ((hi ^ sw) << 3);          // d-half 0 / key-half 0
  const int offA1 = lo * 64 + (((hi + 4) ^ sw) << 3);    // d-half 1 / key-half 1

  // ================= phase 1: denominators (16 x 128-key tiles) ==========
  float lsum = 0.f;
#pragma unroll
  for (int c = 0; c < 4; ++c)
    load_lds16(kg + (size_t)c * 32 * D_, &smem[c * 2048 + t * 8]);
  __syncthreads();

  for (int kc = 0; kc < 16; ++kc) {
    const int cur = kc & 1;
    if (kc < 15) {
      const unsigned short* src = kg + (size_t)(kc + 1) * 128 * D_;
      unsigned short* dst = &smem[(cur ^ 1) * 8192 + t * 8];
#pragma unroll
      for (int c = 0; c < 4; ++c)
        load_lds16(src + (size_t)c * 32 * D_, dst + c * 2048);
    }
    unsigned mwz[4];
#pragma unroll
    for (int w = 0; w < 4; ++w) mwz[w] = mptr[4 * kc + w];
    const unsigned short* kl = &smem[cur * 8192];

    __builtin_amdgcn_s_setprio(1);
    f32x4 a[8];
#pragma unroll
    for (int g = 0; g < 8; ++g) {
      bf16x8 A0 = *reinterpret_cast<const bf16x8*>(kl + g * 1024 + offA0);
      bf16x8 A1 = *reinterpret_cast<const bf16x8*>(kl + g * 1024 + offA1);
      f32x4 acc = {0.f, 0.f, 0.f, 0.f};
      acc = MFMA16(A0, bq0, acc);
      a[g] = MFMA16(A1, bq1, acc);
    }
    __builtin_amdgcn_s_setprio(0);

#pragma unroll
    for (int g = 0; g < 8; ++g) {
      unsigned bits = mwz[g >> 1] >> ((g & 1) * 16);
#pragma unroll
      for (int i = 0; i < 4; ++i)
        lsum += ((bits >> (4 * hi + i)) & 1u) ? 0.f : __expf(a[g][i]);
    }
    __syncthreads();
  }

  lsum += __shfl_xor(lsum, 16, 64);
  lsum += __shfl_xor(lsum, 32, 64);
  const float rinv = 1.0f / lsum;

  // ================= phase 2: attn write + PV (32 x 64-key tiles) ========
  f32x4 oacc[4];
#pragma unroll
  for (int db = 0; db < 4; ++db) {
    oacc[db][0] = 0.f; oacc[db][1] = 0.f; oacc[db][2] = 0.f; oacc[db][3] = 0.f;
  }

#pragma unroll
  for (int c = 0; c < 2; ++c) {
    load_lds16(kg + (size_t)c * 32 * D_, &smem[c * 2048 + t * 8]);
    load_lds16(vg + (size_t)c * 32 * S_, &smem[8192 + c * 2048 + t * 8]);
  }
  __syncthreads();

  for (int kc = 0; kc < 32; ++kc) {
    const int cur = kc & 1;
    if (kc < 31) {
      const unsigned short* ks = kg + (size_t)(kc + 1) * 64 * D_;
      const unsigned short* vs = vg + (kc + 1) * 64;
      unsigned short* kd = &smem[(cur ^ 1) * 4096 + t * 8];
      unsigned short* vd = &smem[8192 + (cur ^ 1) * 4096 + t * 8];
#pragma unroll
      for (int c = 0; c < 2; ++c) {
        load_lds16(ks + (size_t)c * 32 * D_, kd + c * 2048);
        load_lds16(vs + (size_t)c * 32 * S_, vd + c * 2048);
      }
    }
    unsigned mw0 = mptr[2 * kc], mw1 = mptr[2 * kc + 1];
    const unsigned short* kl = &smem[cur * 4096];
    const unsigned short* vl = &smem[8192 + cur * 4096];

    __builtin_amdgcn_s_setprio(1);
    f32x4 a[4];
#pragma unroll
    for (int g = 0; g < 4; ++g) {
      bf16x8 A0 = *reinterpret_cast<const bf16x8*>(kl + g * 1024 + offA0);
      bf16x8 A1 = *reinterpret_cast<const bf16x8*>(kl + g * 1024 + offA1);
      f32x4 acc = {0.f, 0.f, 0.f, 0.f};
      acc = MFMA16(A0, bq0, acc);
      a[g] = MFMA16(A1, bq1, acc);
    }
    __builtin_amdgcn_s_setprio(0);

#pragma unroll
    for (int H = 0; H < 2; ++H) {
      const unsigned bits = (H == 0) ? mw0 : mw1;
      f32x4 p0, p1;
#pragma unroll
      for (int i = 0; i < 4; ++i) {
        p0[i] = ((bits >> (4 * hi + i)) & 1u) ? 0.f
                : __expf(a[2 * H][i]) * rinv;
        p1[i] = ((bits >> (16 + 4 * hi + i)) & 1u) ? 0.f
                : __expf(a[2 * H + 1][i]) * rinv;
      }
      // attn store: keys kc*64 + H*32 + {4hi.., 16+4hi..} of query row q0+lo
      __builtin_nontemporal_store(p0,
          reinterpret_cast<f32x4*>(sp + kc * 64 + H * 32 + 4 * hi));
      __builtin_nontemporal_store(p1,
          reinterpret_cast<f32x4*>(sp + kc * 64 + H * 32 + 16 + 4 * hi));

      // regroup P into PV A-fragment (keys hi*8+j of this 32-key half)
      unsigned pk0 = pack2bf(p0[0], p0[1]), pk1 = pack2bf(p0[2], p0[3]);
      unsigned pk2 = pack2bf(p1[0], p1[1]), pk3 = pack2bf(p1[2], p1[3]);
      unsigned t00 = (unsigned)__shfl((int)pk0, s0, 64);
      unsigned t20 = (unsigned)__shfl((int)pk2, s0, 64);
      unsigned t10 = (unsigned)__shfl((int)pk1, s0, 64);
      unsigned t30 = (unsigned)__shfl((int)pk3, s0, 64);
      unsigned t01 = (unsigned)__shfl((int)pk0, s1, 64);
      unsigned t21 = (unsigned)__shfl((int)pk2, s1, 64);
      unsigned t11 = (unsigned)__shfl((int)pk1, s1, 64);
      unsigned t31 = (unsigned)__shfl((int)pk3, s1, 64);
      uint4 dw;
      dw.x = hl ? t00 : t20; dw.y = hl ? t10 : t30;
      dw.z = hl ? t01 : t21; dw.w = hl ? t11 : t31;
      bf16x8 pa = __builtin_bit_cast(bf16x8, dw);

      const int offV = (H == 0) ? offA0 : offA1;
      __builtin_amdgcn_s_setprio(1);
#pragma unroll
      for (int db = 0; db < 4; ++db) {
        bf16x8 bv = *reinterpret_cast<const bf16x8*>(vl + db * 1024 + offV);
        oacc[db] = MFMA16(pa, bv, oacc[db]);
      }
      __builtin_amdgcn_s_setprio(0);
    }
    __syncthreads();
  }

  // epilogue: O store. D col=d16=lo, row=query=hi*4+i
#pragma unroll
  for (int db = 0; db < 4; ++db)
#pragma unroll
    for (int i = 0; i < 4; ++i)
      __builtin_nontemporal_store(oacc[db][i],
          outO + (size_t)(q0 + hi * 4 + i) * D_ + db * 16 + lo);
}

extern "C" void kernel_launch(void* const* d_in, const int* in_sizes, int n_in,
                              void* d_out, int out_size, void* d_ws, size_t ws_size,
                              hipStream_t stream) {
  const float* q = (const float*)d_in[0];
  const float* k = (const float*)d_in[1];
  const float* v = (const float*)d_in[2];
  const void*  m = d_in[3];
  float* out = (float*)d_out;

  // ws: [0] flag; [256] Vt bf16 (8MB); [+8MB] Kbf bf16 (8MB); [+8MB] Mp (16MB)
  int* flag = (int*)d_ws;
  unsigned short* Vt  = (unsigned short*)((char*)d_ws + 256);
  unsigned short* Kbf = (unsigned short*)((char*)d_ws + 256 + (size_t)B_ * D_ * S_ * 2);
  unsigned*       Mp  = (unsigned*)((char*)d_ws + 256 + (size_t)B_ * D_ * S_ * 4);

  detect_mask<<<1, 64, 0, stream>>>((const unsigned*)m, flag);
  cast_k<<<(B_ * S_ * D_) / (256 * 4), 256, 0, stream>>>(k, Kbf);
  transpose_v<<<dim3(S_ / 32, D_ / 32, B_), dim3(32, 8), 0, stream>>>(v, Vt);
  pack_mask<<<(B_ * S_ * (S_ / 32)) / 256, 256, 0, stream>>>(m, flag, Mp);
  attn_main5<<<B_ * (S_ / 64), 256, 0, stream>>>(q, Kbf, Mp, Vt, out);
}